// Round 7
// baseline (149.017 us; speedup 1.0000x reference)
//
#include <hip/hip_runtime.h>

// ModuleCollect: out[i] = concat(x[i], masked_gather(x, idx[i,0..3]))
// x: [N, 256] f32, indices: [N,4] int (-1 = masked -> zeros), out: [N, 1280] f32
//
// INVERTED-INDEX formulation (round 6) — reads x exactly once (102 MB)
// and scatters each source row to its referencing output segments.
// Traffic: 512 MB W + 102 MB R + ~16 MB aux ~= 630 MB.
//
// Round-7 change: scatter stores are NORMAL (cached), not non-temporal.
// Rationale: random 1 KB nt-stores appear to bypass the memory-side
// Infinity Cache and thrash DRAM pages (~4.3 TB/s effective in round 6).
// Normal stores let the MALL absorb the 1 KB bursts and write back
// lazily/batched. The *sequential* self-segment store keeps nt (proved
// +24 us in the forward kernel).

typedef float f32x4 __attribute__((ext_vector_type(4)));

#define D 256
#define D4 (D / 4)        // 64 f32x4 per row of x
#define OUTW4 (5 * D / 4) // 320 f32x4 per output row
#define CAP 16            // bucket capacity; Poisson(4) tail beyond 16 ~ 5e-6/row
#define OVF_CAP 65536

__global__ __launch_bounds__(256) void zero_counts_kernel(int* counts, int* ovf_cnt, int n)
{
    int i = blockIdx.x * blockDim.x + threadIdx.x;
    if (i == 0) *ovf_cnt = 0;
    if (i < n) counts[i] = 0;
}

__global__ __launch_bounds__(256) void build_buckets_kernel(
    const int* __restrict__ indices, int* counts, int* buckets,
    int* ovf, int* ovf_cnt, int n4)
{
    int e = blockIdx.x * blockDim.x + threadIdx.x;
    if (e >= n4) return;
    int t = indices[e];
    if (t < 0) return;
    int pos = atomicAdd(&counts[t], 1);
    if (pos < CAP) {
        buckets[t * CAP + pos] = e;      // e encodes dest*4+slot
    } else {
        int o = atomicAdd(ovf_cnt, 1);
        if (o < OVF_CAP) ovf[o] = e;
    }
}

__global__ __launch_bounds__(256) void scatter_kernel(
    const f32x4* __restrict__ x4,       // [N * 64]
    const int*   __restrict__ indices,  // [N * 4]
    const int*   __restrict__ counts,
    const int*   __restrict__ buckets,
    f32x4*       __restrict__ out4,     // [N * 320]
    int n)
{
    const int wave = threadIdx.x >> 6;
    const int lane = threadIdx.x & 63;
    const int r = blockIdx.x * 4 + wave;
    if (r >= n) return;

    // source row, read exactly once kernel-wide
    const f32x4 v = __builtin_nontemporal_load(&x4[(long)r * D4 + lane]);

    // self segment: sequential stream -> nt
    __builtin_nontemporal_store(v, &out4[(long)r * OUTW4 + lane]);

    // zero-fill own masked slots (rare)
    const f32x4 zero = (f32x4){0.f, 0.f, 0.f, 0.f};
    #pragma unroll
    for (int s = 0; s < 4; ++s) {
        if (indices[r * 4 + s] < 0)
            out4[(long)r * OUTW4 + (1 + s) * D4 + lane] = zero;
    }

    // scatter to referencing outputs: random 1 KB bursts -> NORMAL stores
    // (let Infinity Cache absorb and batch the write-backs)
    int cnt = counts[r];
    if (cnt > CAP) cnt = CAP;
    for (int j = 0; j < cnt; ++j) {
        int e = buckets[r * CAP + j];
        int dest = e >> 2, slot = e & 3;
        out4[(long)dest * OUTW4 + (1 + slot) * D4 + lane] = v;
    }
}

__global__ __launch_bounds__(256) void overflow_fixup_kernel(
    const f32x4* __restrict__ x4, const int* __restrict__ indices,
    const int* __restrict__ ovf, const int* __restrict__ ovf_cnt,
    f32x4* __restrict__ out4)
{
    const int wave = threadIdx.x >> 6;
    const int lane = threadIdx.x & 63;
    const int gw = blockIdx.x * 4 + wave;
    const int nwaves = gridDim.x * 4;
    int cnt = *ovf_cnt;
    if (cnt > OVF_CAP) cnt = OVF_CAP;
    for (int i = gw; i < cnt; i += nwaves) {
        int e = ovf[i];
        int row = e >> 2, slot = e & 3;
        int t = indices[e];                      // >= 0 by construction
        f32x4 v = x4[(long)t * D4 + lane];
        out4[(long)row * OUTW4 + (1 + slot) * D4 + lane] = v;
    }
}

// ---- fallback: plain forward kernel ----
__global__ __launch_bounds__(256) void collect_fwd_kernel(
    const f32x4* __restrict__ x4, const int* __restrict__ indices,
    f32x4* __restrict__ out4, int n)
{
    const int wave = threadIdx.x >> 6;
    const int lane = threadIdx.x & 63;
    const int row  = blockIdx.x * 4 + wave;
    if (row >= n) return;
    const f32x4* xrow = x4 + (long)row * D4;
    f32x4* orow = out4 + (long)row * OUTW4;
    const int i0 = indices[row * 4 + 0];
    const int i1 = indices[row * 4 + 1];
    const int i2 = indices[row * 4 + 2];
    const int i3 = indices[row * 4 + 3];
    const f32x4 zero = (f32x4){0.f, 0.f, 0.f, 0.f};
    f32x4 v_self = xrow[lane];
    f32x4 v0 = (i0 >= 0) ? x4[(long)i0 * D4 + lane] : zero;
    f32x4 v1 = (i1 >= 0) ? x4[(long)i1 * D4 + lane] : zero;
    f32x4 v2 = (i2 >= 0) ? x4[(long)i2 * D4 + lane] : zero;
    f32x4 v3 = (i3 >= 0) ? x4[(long)i3 * D4 + lane] : zero;
    __builtin_nontemporal_store(v_self, &orow[lane]);
    __builtin_nontemporal_store(v0, &orow[D4 * 1 + lane]);
    __builtin_nontemporal_store(v1, &orow[D4 * 2 + lane]);
    __builtin_nontemporal_store(v2, &orow[D4 * 3 + lane]);
    __builtin_nontemporal_store(v3, &orow[D4 * 4 + lane]);
}

extern "C" void kernel_launch(void* const* d_in, const int* in_sizes, int n_in,
                              void* d_out, int out_size, void* d_ws, size_t ws_size,
                              hipStream_t stream)
{
    const f32x4* x4 = (const f32x4*)d_in[0];
    const int* indices = (const int*)d_in[1];
    f32x4* out4 = (f32x4*)d_out;

    const int n  = in_sizes[0] / D;   // 100000
    const int n4 = in_sizes[1];       // 400000

    // ws layout (64B-aligned fields)
    size_t off_counts  = 0;                                   // n ints
    size_t off_ovfcnt  = (size_t)((n * 4 + 63) / 64) * 64;    // 1 int
    size_t off_ovf     = off_ovfcnt + 64;                     // OVF_CAP ints
    size_t off_buckets = off_ovf + (size_t)OVF_CAP * 4;       // n*CAP ints
    size_t need = off_buckets + (size_t)n * CAP * 4;

    dim3 block(256);

    if (ws_size < need) {
        collect_fwd_kernel<<<dim3((n + 3) / 4), block, 0, stream>>>(x4, indices, out4, n);
        return;
    }

    char* ws = (char*)d_ws;
    int* counts  = (int*)(ws + off_counts);
    int* ovf_cnt = (int*)(ws + off_ovfcnt);
    int* ovf     = (int*)(ws + off_ovf);
    int* buckets = (int*)(ws + off_buckets);

    zero_counts_kernel<<<dim3((n + 255) / 256), block, 0, stream>>>(counts, ovf_cnt, n);
    build_buckets_kernel<<<dim3((n4 + 255) / 256), block, 0, stream>>>(
        indices, counts, buckets, ovf, ovf_cnt, n4);
    scatter_kernel<<<dim3((n + 3) / 4), block, 0, stream>>>(
        x4, indices, counts, buckets, out4, n);
    overflow_fixup_kernel<<<dim3(8), block, 0, stream>>>(
        x4, indices, ovf, ovf_cnt, out4);
}